// Round 2
// baseline (561.037 us; speedup 1.0000x reference)
//
#include <hip/hip_runtime.h>
#include <hip/hip_bf16.h>

// 2-layer GCN on MI355X.
// out[v] = dinv[v] * ( sum_{e: dst=v} g[src_e] + g[v] ) + b,  g = (x@W) * dinv[row]
// dinv[v] = rsqrt(indeg(v) + 1)   (reference: deg from dst only, self-loops added)
// NOTE: harness passes ALL integer inputs as int32 — edge_index is const int*.

#define FDIM 64   // HID_DIM == OUT_DIM == 64 == one wave of lanes

// ---------------- init counts & cursor ----------------
__global__ __launch_bounds__(256) void init_int2(int* __restrict__ a, int* __restrict__ b, int n) {
    int i = blockIdx.x * 256 + threadIdx.x;
    if (i < n) { a[i] = 0; b[i] = 0; }
}

// ---------------- count in-degree ----------------
__global__ __launch_bounds__(256) void count_edges(const int* __restrict__ dst,
                                                   int* __restrict__ counts, int E) {
    int e = blockIdx.x * 256 + threadIdx.x;
    if (e < E) atomicAdd(&counts[dst[e]], 1);
}

// ---------------- dinv = rsqrt(count+1) ----------------
__global__ __launch_bounds__(256) void compute_dinv(const int* __restrict__ counts,
                                                    float* __restrict__ dinv, int N) {
    int i = blockIdx.x * 256 + threadIdx.x;
    if (i < N) dinv[i] = rsqrtf((float)(counts[i] + 1));
}

// ---------------- scan pass A: per-block sums ----------------
__global__ __launch_bounds__(256) void scan_block_sums(const int* __restrict__ counts,
                                                       int* __restrict__ blockSums, int N) {
    __shared__ int sdata[256];
    int i = blockIdx.x * 256 + threadIdx.x;
    sdata[threadIdx.x] = (i < N) ? counts[i] : 0;
    __syncthreads();
    for (int s = 128; s > 0; s >>= 1) {
        if (threadIdx.x < s) sdata[threadIdx.x] += sdata[threadIdx.x + s];
        __syncthreads();
    }
    if (threadIdx.x == 0) blockSums[blockIdx.x] = sdata[0];
}

// ---------------- scan pass B: exclusive scan of block sums (1 block, 512 thr) ---
__global__ __launch_bounds__(512) void scan_mid(int* __restrict__ blockSums, int nB,
                                                int* __restrict__ rowStart, int N) {
    __shared__ int s[512];
    int t = threadIdx.x;
    int v = (t < nB) ? blockSums[t] : 0;
    s[t] = v;
    __syncthreads();
    for (int off = 1; off < 512; off <<= 1) {
        int x = s[t];
        int y = (t >= off) ? s[t - off] : 0;
        __syncthreads();
        s[t] = x + y;
        __syncthreads();
    }
    if (t < nB) blockSums[t] = s[t] - v;     // exclusive block offset
    if (t == 511) rowStart[N] = s[511];      // total == E
}

// ---------------- scan pass C: final rowStart (+ seed cursor) ----------------
__global__ __launch_bounds__(256) void scan_final(const int* __restrict__ counts,
                                                  const int* __restrict__ blockOff,
                                                  int* __restrict__ rowStart, int N) {
    __shared__ int s[256];
    int i = blockIdx.x * 256 + threadIdx.x;
    int v = (i < N) ? counts[i] : 0;
    s[threadIdx.x] = v;
    __syncthreads();
    for (int off = 1; off < 256; off <<= 1) {
        int x = s[threadIdx.x];
        int y = (threadIdx.x >= off) ? s[threadIdx.x - off] : 0;
        __syncthreads();
        s[threadIdx.x] = x + y;
        __syncthreads();
    }
    if (i < N) rowStart[i] = blockOff[blockIdx.x] + s[threadIdx.x] - v;
}

// ---------------- scatter edges into CSR ----------------
__global__ __launch_bounds__(256) void scatter_edges(const int* __restrict__ src,
                                                     const int* __restrict__ dst,
                                                     const int* __restrict__ rowStart,
                                                     int* __restrict__ cursor,
                                                     int* __restrict__ srcSorted, int E) {
    int e = blockIdx.x * 256 + threadIdx.x;
    if (e < E) {
        int d = dst[e];
        int pos = rowStart[d] + atomicAdd(&cursor[d], 1);
        srcSorted[pos] = src[e];
    }
}

// ---------------- GEMM: one wave per row, W column-stationary in VGPRs --------
// g[row][lane] = dinv[row] * sum_k X[row][k] * W[k*64+lane]
template <int K>
__global__ __launch_bounds__(256) void gemm_scale(const float* __restrict__ X,
                                                  const float* __restrict__ W,
                                                  const float* __restrict__ dinv,
                                                  float* __restrict__ G, int N) {
    const int lane   = threadIdx.x & 63;
    const int waveId = blockIdx.x * (blockDim.x >> 6) + (threadIdx.x >> 6);
    const int nWaves = gridDim.x * (blockDim.x >> 6);

    float w[K];
    #pragma unroll
    for (int k = 0; k < K; ++k) w[k] = W[k * FDIM + lane];

    for (int row = waveId; row < N; row += nWaves) {
        const float4* xr = reinterpret_cast<const float4*>(X + (size_t)row * K);
        float a0 = 0.f, a1 = 0.f, a2 = 0.f, a3 = 0.f;
        #pragma unroll
        for (int k4 = 0; k4 < K / 4; ++k4) {
            float4 xv = xr[k4];
            a0 += xv.x * w[4 * k4 + 0];
            a1 += xv.y * w[4 * k4 + 1];
            a2 += xv.z * w[4 * k4 + 2];
            a3 += xv.w * w[4 * k4 + 3];
        }
        G[(size_t)row * FDIM + lane] = ((a0 + a1) + (a2 + a3)) * dinv[row];
    }
}

// ---------------- aggregate: one wave per node, no atomics ----------------
__global__ __launch_bounds__(256) void aggregate(const float* __restrict__ G,
                                                 const int* __restrict__ rowStart,
                                                 const int* __restrict__ srcSorted,
                                                 const float* __restrict__ dinv,
                                                 const float* __restrict__ bias,
                                                 float* __restrict__ OUT, int N, int doRelu) {
    const int lane   = threadIdx.x & 63;
    const int waveId = blockIdx.x * (blockDim.x >> 6) + (threadIdx.x >> 6);
    const int nWaves = gridDim.x * (blockDim.x >> 6);
    const float b = bias[lane];

    for (int v = waveId; v < N; v += nWaves) {
        int beg = rowStart[v], end = rowStart[v + 1];
        float acc = G[(size_t)v * FDIM + lane];   // self loop (g[v])
        int e = beg;
        for (; e + 4 <= end; e += 4) {
            int s0 = srcSorted[e + 0];
            int s1 = srcSorted[e + 1];
            int s2 = srcSorted[e + 2];
            int s3 = srcSorted[e + 3];
            float v0 = G[(size_t)s0 * FDIM + lane];
            float v1 = G[(size_t)s1 * FDIM + lane];
            float v2 = G[(size_t)s2 * FDIM + lane];
            float v3 = G[(size_t)s3 * FDIM + lane];
            acc += v0; acc += v1; acc += v2; acc += v3;
        }
        for (; e < end; ++e) {
            int s0 = srcSorted[e];
            acc += G[(size_t)s0 * FDIM + lane];
        }
        float r = acc * dinv[v] + b;
        if (doRelu) r = fmaxf(r, 0.f);
        OUT[(size_t)v * FDIM + lane] = r;
    }
}

extern "C" void kernel_launch(void* const* d_in, const int* in_sizes, int n_in,
                              void* d_out, int out_size, void* d_ws, size_t ws_size,
                              hipStream_t stream) {
    const float* x     = (const float*)d_in[0];
    const int*   edges = (const int*)d_in[1];   // int32 per harness contract
    const float* W1    = (const float*)d_in[2];
    const float* b1    = (const float*)d_in[3];
    const float* W2    = (const float*)d_in[4];
    const float* b2    = (const float*)d_in[5];
    float*       out   = (float*)d_out;

    const int N = in_sizes[0] / 128;   // 100000
    const int E = in_sizes[1] / 2;     // 1600000
    const int* srcIdx = edges;
    const int* dstIdx = edges + E;

    // workspace layout (256B aligned slices), total ~59 MB
    char* ws = (char*)d_ws;
    size_t off = 0;
    auto alloc = [&](size_t bytes) { char* p = ws + off; off = (off + bytes + 255) & ~(size_t)255; return p; };
    float* dinv      = (float*)alloc((size_t)N * 4);
    int*   counts    = (int*)  alloc((size_t)N * 4);
    int*   cursor    = (int*)  alloc((size_t)N * 4);
    int*   blockSums = (int*)  alloc(512 * 4);
    int*   rowStart  = (int*)  alloc((size_t)(N + 1) * 4);
    int*   srcSorted = (int*)  alloc((size_t)E * 4);
    float* g1        = (float*)alloc((size_t)N * FDIM * 4);
    float* x2        = (float*)alloc((size_t)N * FDIM * 4);
    float* g2        = g1;   // g1 dead after first aggregate

    const int nB = (N + 255) / 256;     // 391 (<= 512 for scan_mid)
    const int gN = (N + 255) / 256;
    const int gE = (E + 255) / 256;

    init_int2      <<<gN, 256, 0, stream>>>(counts, cursor, N);
    count_edges    <<<gE, 256, 0, stream>>>(dstIdx, counts, E);
    compute_dinv   <<<gN, 256, 0, stream>>>(counts, dinv, N);
    scan_block_sums<<<nB, 256, 0, stream>>>(counts, blockSums, N);
    scan_mid       <<<1, 512, 0, stream>>>(blockSums, nB, rowStart, N);
    scan_final     <<<nB, 256, 0, stream>>>(counts, blockSums, rowStart, N);
    scatter_edges  <<<gE, 256, 0, stream>>>(srcIdx, dstIdx, rowStart, cursor, srcSorted, E);

    gemm_scale<128><<<2048, 256, 0, stream>>>(x,  W1, dinv, g1, N);
    aggregate      <<<2048, 256, 0, stream>>>(g1, rowStart, srcSorted, dinv, b1, x2, N, 1);
    gemm_scale<64> <<<2048, 256, 0, stream>>>(x2, W2, dinv, g2, N);
    aggregate      <<<2048, 256, 0, stream>>>(g2, rowStart, srcSorted, dinv, b2, out, N, 0);
}

// Round 3
// 363.281 us; speedup vs baseline: 1.5444x; 1.5444x over previous
//
#include <hip/hip_runtime.h>
#include <hip/hip_bf16.h>

// 2-layer GCN on MI355X.
// out[v] = dinv[v] * ( sum_{e: dst=v} g[src_e] + g[v] ) + b,  g = (x@W) * dinv[row]
// dinv[v] = rsqrt(indeg(v) + 1)   (reference: deg from dst only, self-loops added)
// edge_index arrives as int32 (harness converts int64 -> int).

#define FDIM 64   // HID_DIM == OUT_DIM == 64

// ---------------- init counts & cursor ----------------
__global__ __launch_bounds__(256) void init_int2(int* __restrict__ a, int* __restrict__ b, int n) {
    int i = blockIdx.x * 256 + threadIdx.x;
    if (i < n) { a[i] = 0; b[i] = 0; }
}

// ---------------- count in-degree ----------------
__global__ __launch_bounds__(256) void count_edges(const int* __restrict__ dst,
                                                   int* __restrict__ counts, int E) {
    int e = blockIdx.x * 256 + threadIdx.x;
    if (e < E) atomicAdd(&counts[dst[e]], 1);
}

// ---------------- dinv = rsqrt(count+1) ----------------
__global__ __launch_bounds__(256) void compute_dinv(const int* __restrict__ counts,
                                                    float* __restrict__ dinv, int N) {
    int i = blockIdx.x * 256 + threadIdx.x;
    if (i < N) dinv[i] = rsqrtf((float)(counts[i] + 1));
}

// ---------------- scan pass A: per-block sums ----------------
__global__ __launch_bounds__(256) void scan_block_sums(const int* __restrict__ counts,
                                                       int* __restrict__ blockSums, int N) {
    __shared__ int sdata[256];
    int i = blockIdx.x * 256 + threadIdx.x;
    sdata[threadIdx.x] = (i < N) ? counts[i] : 0;
    __syncthreads();
    for (int s = 128; s > 0; s >>= 1) {
        if (threadIdx.x < s) sdata[threadIdx.x] += sdata[threadIdx.x + s];
        __syncthreads();
    }
    if (threadIdx.x == 0) blockSums[blockIdx.x] = sdata[0];
}

// ---------------- scan pass B: exclusive scan of block sums (1 block, 512 thr) ---
__global__ __launch_bounds__(512) void scan_mid(int* __restrict__ blockSums, int nB,
                                                int* __restrict__ rowStart, int N) {
    __shared__ int s[512];
    int t = threadIdx.x;
    int v = (t < nB) ? blockSums[t] : 0;
    s[t] = v;
    __syncthreads();
    for (int off = 1; off < 512; off <<= 1) {
        int x = s[t];
        int y = (t >= off) ? s[t - off] : 0;
        __syncthreads();
        s[t] = x + y;
        __syncthreads();
    }
    if (t < nB) blockSums[t] = s[t] - v;     // exclusive block offset
    if (t == 511) rowStart[N] = s[511];      // total == E
}

// ---------------- scan pass C: final rowStart ----------------
__global__ __launch_bounds__(256) void scan_final(const int* __restrict__ counts,
                                                  const int* __restrict__ blockOff,
                                                  int* __restrict__ rowStart, int N) {
    __shared__ int s[256];
    int i = blockIdx.x * 256 + threadIdx.x;
    int v = (i < N) ? counts[i] : 0;
    s[threadIdx.x] = v;
    __syncthreads();
    for (int off = 1; off < 256; off <<= 1) {
        int x = s[threadIdx.x];
        int y = (threadIdx.x >= off) ? s[threadIdx.x - off] : 0;
        __syncthreads();
        s[threadIdx.x] = x + y;
        __syncthreads();
    }
    if (i < N) rowStart[i] = blockOff[blockIdx.x] + s[threadIdx.x] - v;
}

// ---------------- scatter edges into CSR ----------------
__global__ __launch_bounds__(256) void scatter_edges(const int* __restrict__ src,
                                                     const int* __restrict__ dst,
                                                     const int* __restrict__ rowStart,
                                                     int* __restrict__ cursor,
                                                     int* __restrict__ srcSorted, int E) {
    int e = blockIdx.x * 256 + threadIdx.x;
    if (e < E) {
        int d = dst[e];
        int pos = rowStart[d] + atomicAdd(&cursor[d], 1);
        srcSorted[pos] = src[e];
    }
}

// ---------------- GEMM: W in LDS, 16 outputs/thread in registers -------------
// Block = 256 threads, 64 rows/block. Thread t: row t/4, col-quarter t%4
// (cols 16q..16q+15). g[row][c] = dinv[row] * sum_k X[row][k]*W[k][c].
// VGPR ~60 (acc16 + xv4 + w16 + addr) -> high occupancy; W reads are
// lane-broadcast b128 (<=2-way bank alias = free).
template <int K>
__global__ __launch_bounds__(256) void gemm_scale(const float* __restrict__ X,
                                                  const float* __restrict__ W,
                                                  const float* __restrict__ dinv,
                                                  float* __restrict__ G, int N) {
    __shared__ float Wl[K * FDIM];
    const int t = threadIdx.x;

    // stage W -> LDS (K*64 floats, float4 per thread per iter)
    {
        const float4* Wv  = reinterpret_cast<const float4*>(W);
        float4*       Wlv = reinterpret_cast<float4*>(Wl);
        #pragma unroll
        for (int i = 0; i < (K * FDIM) / (256 * 4); ++i)
            Wlv[i * 256 + t] = Wv[i * 256 + t];
    }
    __syncthreads();

    const int r   = t >> 2;                  // 0..63
    const int q   = t & 3;                   // col quarter
    const int row = blockIdx.x * 64 + r;
    if (row >= N) return;                    // no barriers after this point

    const float4* xr  = reinterpret_cast<const float4*>(X + (size_t)row * K);
    const float4* wlq = reinterpret_cast<const float4*>(Wl) + q * 4;  // +16q floats

    float acc[16];
    #pragma unroll
    for (int i = 0; i < 16; ++i) acc[i] = 0.f;

    #pragma unroll 2
    for (int k4 = 0; k4 < K / 4; ++k4) {
        float4 xv = xr[k4];
        float xs[4] = {xv.x, xv.y, xv.z, xv.w};
        #pragma unroll
        for (int j = 0; j < 4; ++j) {
            const float4* wrow = wlq + (size_t)(4 * k4 + j) * 16;  // row k: 16 float4
            float4 w0 = wrow[0], w1 = wrow[1], w2 = wrow[2], w3 = wrow[3];
            float xk = xs[j];
            acc[ 0] += xk * w0.x; acc[ 1] += xk * w0.y; acc[ 2] += xk * w0.z; acc[ 3] += xk * w0.w;
            acc[ 4] += xk * w1.x; acc[ 5] += xk * w1.y; acc[ 6] += xk * w1.z; acc[ 7] += xk * w1.w;
            acc[ 8] += xk * w2.x; acc[ 9] += xk * w2.y; acc[10] += xk * w2.z; acc[11] += xk * w2.w;
            acc[12] += xk * w3.x; acc[13] += xk * w3.y; acc[14] += xk * w3.z; acc[15] += xk * w3.w;
        }
    }

    const float dv = dinv[row];
    float4* gout = reinterpret_cast<float4*>(G + (size_t)row * FDIM + q * 16);
    #pragma unroll
    for (int c4 = 0; c4 < 4; ++c4) {
        float4 o;
        o.x = acc[4 * c4 + 0] * dv;
        o.y = acc[4 * c4 + 1] * dv;
        o.z = acc[4 * c4 + 2] * dv;
        o.w = acc[4 * c4 + 3] * dv;
        gout[c4] = o;
    }
}

// ---------------- aggregate: one wave per node, no atomics ----------------
__global__ __launch_bounds__(256) void aggregate(const float* __restrict__ G,
                                                 const int* __restrict__ rowStart,
                                                 const int* __restrict__ srcSorted,
                                                 const float* __restrict__ dinv,
                                                 const float* __restrict__ bias,
                                                 float* __restrict__ OUT, int N, int doRelu) {
    const int lane   = threadIdx.x & 63;
    const int waveId = blockIdx.x * (blockDim.x >> 6) + (threadIdx.x >> 6);
    const int nWaves = gridDim.x * (blockDim.x >> 6);
    const float b = bias[lane];

    for (int v = waveId; v < N; v += nWaves) {
        int beg = rowStart[v], end = rowStart[v + 1];
        float acc = G[(size_t)v * FDIM + lane];   // self loop (g[v])
        int e = beg;
        for (; e + 4 <= end; e += 4) {
            int s0 = srcSorted[e + 0];
            int s1 = srcSorted[e + 1];
            int s2 = srcSorted[e + 2];
            int s3 = srcSorted[e + 3];
            float v0 = G[(size_t)s0 * FDIM + lane];
            float v1 = G[(size_t)s1 * FDIM + lane];
            float v2 = G[(size_t)s2 * FDIM + lane];
            float v3 = G[(size_t)s3 * FDIM + lane];
            acc += v0; acc += v1; acc += v2; acc += v3;
        }
        for (; e < end; ++e) {
            int s0 = srcSorted[e];
            acc += G[(size_t)s0 * FDIM + lane];
        }
        float r = acc * dinv[v] + b;
        if (doRelu) r = fmaxf(r, 0.f);
        OUT[(size_t)v * FDIM + lane] = r;
    }
}

extern "C" void kernel_launch(void* const* d_in, const int* in_sizes, int n_in,
                              void* d_out, int out_size, void* d_ws, size_t ws_size,
                              hipStream_t stream) {
    const float* x     = (const float*)d_in[0];
    const int*   edges = (const int*)d_in[1];   // int32 per harness contract
    const float* W1    = (const float*)d_in[2];
    const float* b1    = (const float*)d_in[3];
    const float* W2    = (const float*)d_in[4];
    const float* b2    = (const float*)d_in[5];
    float*       out   = (float*)d_out;

    const int N = in_sizes[0] / 128;   // 100000
    const int E = in_sizes[1] / 2;     // 1600000
    const int* srcIdx = edges;
    const int* dstIdx = edges + E;

    // workspace layout (256B aligned slices), total ~59 MB
    char* ws = (char*)d_ws;
    size_t off = 0;
    auto alloc = [&](size_t bytes) { char* p = ws + off; off = (off + bytes + 255) & ~(size_t)255; return p; };
    float* dinv      = (float*)alloc((size_t)N * 4);
    int*   counts    = (int*)  alloc((size_t)N * 4);
    int*   cursor    = (int*)  alloc((size_t)N * 4);
    int*   blockSums = (int*)  alloc(512 * 4);
    int*   rowStart  = (int*)  alloc((size_t)(N + 1) * 4);
    int*   srcSorted = (int*)  alloc((size_t)E * 4);
    float* g1        = (float*)alloc((size_t)N * FDIM * 4);
    float* x2        = (float*)alloc((size_t)N * FDIM * 4);
    float* g2        = g1;   // g1 dead after first aggregate

    const int nB = (N + 255) / 256;     // 391 (<= 512 for scan_mid)
    const int gN = (N + 255) / 256;
    const int gE = (E + 255) / 256;
    const int gT = (N + 63) / 64;       // 64-row GEMM tiles

    init_int2      <<<gN, 256, 0, stream>>>(counts, cursor, N);
    count_edges    <<<gE, 256, 0, stream>>>(dstIdx, counts, E);
    compute_dinv   <<<gN, 256, 0, stream>>>(counts, dinv, N);
    scan_block_sums<<<nB, 256, 0, stream>>>(counts, blockSums, N);
    scan_mid       <<<1, 512, 0, stream>>>(blockSums, nB, rowStart, N);
    scan_final     <<<nB, 256, 0, stream>>>(counts, blockSums, rowStart, N);
    scatter_edges  <<<gE, 256, 0, stream>>>(srcIdx, dstIdx, rowStart, cursor, srcSorted, E);

    gemm_scale<128><<<gT, 256, 0, stream>>>(x,  W1, dinv, g1, N);
    aggregate      <<<2048, 256, 0, stream>>>(g1, rowStart, srcSorted, dinv, b1, x2, N, 1);
    gemm_scale<64> <<<gT, 256, 0, stream>>>(x2, W2, dinv, g2, N);
    aggregate      <<<2048, 256, 0, stream>>>(g2, rowStart, srcSorted, dinv, b2, out, N, 0);
}

// Round 4
// 251.082 us; speedup vs baseline: 2.2345x; 1.4469x over previous
//
#include <hip/hip_runtime.h>
#include <hip/hip_bf16.h>

// 2-layer GCN on MI355X.
// out[v] = dinv[v] * ( sum_{e: dst=v} g[src_e] + g[v] ) + b,  g = (x@W) * dinv[row]
// dinv[v] = rsqrt(indeg(v) + 1)
// CSR build = bucketed counting sort, ALL atomics in LDS (no device atomics).

#define FDIM 64    // HID_DIM == OUT_DIM
#define NPB  128   // nodes per bucket (dst >> 7)
#define MAXB1 800  // >= ceil(100000/128)=782

// ---------------- phase 1a: per-block bucket histogram ----------------
__global__ __launch_bounds__(256) void bucket_hist(const int* __restrict__ dst, int E,
                                                   int B1, int chunk, int B0,
                                                   int* __restrict__ H) {
    __shared__ int hist[MAXB1];
    const int blk = blockIdx.x, t = threadIdx.x;
    for (int i = t; i < B1; i += 256) hist[i] = 0;
    __syncthreads();
    const int beg = blk * chunk, end = min(E, beg + chunk);
    for (int e = beg + t; e < end; e += 256) atomicAdd(&hist[dst[e] >> 7], 1);
    __syncthreads();
    for (int i = t; i < B1; i += 256) H[i * B0 + blk] = hist[i];  // bin-major
}

// ---------------- scan A: per-block sums over spans of 2048 ----------------
__global__ __launch_bounds__(256) void scanA(const int* __restrict__ a, int S,
                                             int* __restrict__ bs) {
    __shared__ int s[256];
    const int blk = blockIdx.x, t = threadIdx.x;
    const int base = blk * 2048 + t * 8;
    int sum = 0;
    #pragma unroll
    for (int j = 0; j < 8; ++j) { int idx = base + j; if (idx < S) sum += a[idx]; }
    s[t] = sum;
    __syncthreads();
    for (int off = 128; off > 0; off >>= 1) {
        if (t < off) s[t] += s[t + off];
        __syncthreads();
    }
    if (t == 0) bs[blk] = s[0];
}

// ---------------- scan B: exclusive scan of block sums (nB <= 512) ----------
__global__ __launch_bounds__(512) void scanB(int* __restrict__ bs, int nB) {
    __shared__ int s[512];
    const int t = threadIdx.x;
    int v = (t < nB) ? bs[t] : 0;
    s[t] = v;
    __syncthreads();
    for (int off = 1; off < 512; off <<= 1) {
        int x = s[t];
        int y = (t >= off) ? s[t - off] : 0;
        __syncthreads();
        s[t] = x + y;
        __syncthreads();
    }
    if (t < nB) bs[t] = s[t] - v;
}

// ---------------- scan C: in-place exclusive scan (span 2048/block) ---------
__global__ __launch_bounds__(256) void scanC(int* __restrict__ a, int S,
                                             const int* __restrict__ bs) {
    __shared__ int s[256];
    const int blk = blockIdx.x, t = threadIdx.x;
    const int base = blk * 2048 + t * 8;
    int v[8];
    int sum = 0;
    #pragma unroll
    for (int j = 0; j < 8; ++j) { int idx = base + j; v[j] = (idx < S) ? a[idx] : 0; sum += v[j]; }
    s[t] = sum;
    __syncthreads();
    const int own = sum;
    for (int off = 1; off < 256; off <<= 1) {
        int x = s[t];
        int y = (t >= off) ? s[t - off] : 0;
        __syncthreads();
        s[t] = x + y;
        __syncthreads();
    }
    int run = bs[blk] + s[t] - own;   // exclusive prefix for this thread's segment
    #pragma unroll
    for (int j = 0; j < 8; ++j) { int idx = base + j; if (idx < S) a[idx] = run; run += v[j]; }
}

// ---------------- phase 1b: scatter edges into bucket-grouped pairs ---------
__global__ __launch_bounds__(256) void bucket_scatter(const int* __restrict__ src,
                                                      const int* __restrict__ dst,
                                                      int E, int B1, int chunk, int B0,
                                                      const int* __restrict__ Hs,
                                                      int2* __restrict__ pairs) {
    __shared__ int cur[MAXB1];
    const int blk = blockIdx.x, t = threadIdx.x;
    for (int i = t; i < B1; i += 256) cur[i] = Hs[i * B0 + blk];
    __syncthreads();
    const int beg = blk * chunk, end = min(E, beg + chunk);
    for (int e = beg + t; e < end; e += 256) {
        int d = dst[e];
        int pos = atomicAdd(&cur[d >> 7], 1);      // LDS atomic
        pairs[pos] = make_int2(d, src[e]);
    }
}

// ---------------- phase 2: per-bucket local counting sort -> CSR ------------
__global__ __launch_bounds__(256) void bucket_csr(const int2* __restrict__ pairs,
                                                  const int* __restrict__ Hs,
                                                  int B0, int E, int N,
                                                  float* __restrict__ dinv,
                                                  int* __restrict__ rowStart,
                                                  int* __restrict__ srcSorted) {
    __shared__ int hist[NPB], pref[NPB], cur[NPB];
    const int b = blockIdx.x, t = threadIdx.x;
    const int B1 = gridDim.x;
    const int vbase = b * NPB;
    const int nv = min(NPB, N - vbase);
    const int estart = Hs[b * B0];
    const int eend = (b + 1 < B1) ? Hs[(b + 1) * B0] : E;

    if (t < NPB) hist[t] = 0;
    __syncthreads();
    for (int e = estart + t; e < eend; e += 256)
        atomicAdd(&hist[pairs[e].x - vbase], 1);
    __syncthreads();

    if (t < NPB) pref[t] = hist[t];
    __syncthreads();
    for (int off = 1; off < NPB; off <<= 1) {
        int v = 0;
        if (t < NPB && t >= off) v = pref[t - off];
        __syncthreads();
        if (t < NPB) pref[t] += v;
        __syncthreads();
    }
    if (t < nv) {
        int ex = pref[t] - hist[t];          // exclusive prefix
        rowStart[vbase + t] = estart + ex;
        dinv[vbase + t] = rsqrtf((float)(hist[t] + 1));
        cur[t] = estart + ex;
    }
    if (b == B1 - 1 && t == 0) rowStart[N] = E;
    __syncthreads();
    for (int e = estart + t; e < eend; e += 256) {
        int2 p = pairs[e];
        int pos = atomicAdd(&cur[p.x - vbase], 1);   // LDS atomic
        srcSorted[pos] = p.y;
    }
}

// ---------------- GEMM: W in LDS, 16 outputs/thread in registers ------------
template <int K>
__global__ __launch_bounds__(256) void gemm_scale(const float* __restrict__ X,
                                                  const float* __restrict__ W,
                                                  const float* __restrict__ dinv,
                                                  float* __restrict__ G, int N) {
    __shared__ float Wl[K * FDIM];
    const int t = threadIdx.x;
    {
        const float4* Wv  = reinterpret_cast<const float4*>(W);
        float4*       Wlv = reinterpret_cast<float4*>(Wl);
        #pragma unroll
        for (int i = 0; i < (K * FDIM) / (256 * 4); ++i)
            Wlv[i * 256 + t] = Wv[i * 256 + t];
    }
    __syncthreads();

    const int r   = t >> 2;
    const int q   = t & 3;
    const int row = blockIdx.x * 64 + r;
    if (row >= N) return;

    const float4* xr  = reinterpret_cast<const float4*>(X + (size_t)row * K);
    const float4* wlq = reinterpret_cast<const float4*>(Wl) + q * 4;

    float acc[16];
    #pragma unroll
    for (int i = 0; i < 16; ++i) acc[i] = 0.f;

    #pragma unroll 2
    for (int k4 = 0; k4 < K / 4; ++k4) {
        float4 xv = xr[k4];
        float xs[4] = {xv.x, xv.y, xv.z, xv.w};
        #pragma unroll
        for (int j = 0; j < 4; ++j) {
            const float4* wrow = wlq + (size_t)(4 * k4 + j) * 16;
            float4 w0 = wrow[0], w1 = wrow[1], w2 = wrow[2], w3 = wrow[3];
            float xk = xs[j];
            acc[ 0] += xk * w0.x; acc[ 1] += xk * w0.y; acc[ 2] += xk * w0.z; acc[ 3] += xk * w0.w;
            acc[ 4] += xk * w1.x; acc[ 5] += xk * w1.y; acc[ 6] += xk * w1.z; acc[ 7] += xk * w1.w;
            acc[ 8] += xk * w2.x; acc[ 9] += xk * w2.y; acc[10] += xk * w2.z; acc[11] += xk * w2.w;
            acc[12] += xk * w3.x; acc[13] += xk * w3.y; acc[14] += xk * w3.z; acc[15] += xk * w3.w;
        }
    }

    const float dv = dinv[row];
    float4* gout = reinterpret_cast<float4*>(G + (size_t)row * FDIM + q * 16);
    #pragma unroll
    for (int c4 = 0; c4 < 4; ++c4) {
        float4 o;
        o.x = acc[4 * c4 + 0] * dv;
        o.y = acc[4 * c4 + 1] * dv;
        o.z = acc[4 * c4 + 2] * dv;
        o.w = acc[4 * c4 + 3] * dv;
        gout[c4] = o;
    }
}

// ---------------- aggregate: one wave per node, no atomics ----------------
__global__ __launch_bounds__(256) void aggregate(const float* __restrict__ G,
                                                 const int* __restrict__ rowStart,
                                                 const int* __restrict__ srcSorted,
                                                 const float* __restrict__ dinv,
                                                 const float* __restrict__ bias,
                                                 float* __restrict__ OUT, int N, int doRelu) {
    const int lane   = threadIdx.x & 63;
    const int waveId = blockIdx.x * (blockDim.x >> 6) + (threadIdx.x >> 6);
    const int nWaves = gridDim.x * (blockDim.x >> 6);
    const float b = bias[lane];

    for (int v = waveId; v < N; v += nWaves) {
        int beg = rowStart[v], end = rowStart[v + 1];
        float acc = G[(size_t)v * FDIM + lane];   // self loop
        int e = beg;
        for (; e + 4 <= end; e += 4) {
            int s0 = srcSorted[e + 0];
            int s1 = srcSorted[e + 1];
            int s2 = srcSorted[e + 2];
            int s3 = srcSorted[e + 3];
            float v0 = G[(size_t)s0 * FDIM + lane];
            float v1 = G[(size_t)s1 * FDIM + lane];
            float v2 = G[(size_t)s2 * FDIM + lane];
            float v3 = G[(size_t)s3 * FDIM + lane];
            acc += v0; acc += v1; acc += v2; acc += v3;
        }
        for (; e < end; ++e) acc += G[(size_t)srcSorted[e] * FDIM + lane];
        float r = acc * dinv[v] + b;
        if (doRelu) r = fmaxf(r, 0.f);
        OUT[(size_t)v * FDIM + lane] = r;
    }
}

extern "C" void kernel_launch(void* const* d_in, const int* in_sizes, int n_in,
                              void* d_out, int out_size, void* d_ws, size_t ws_size,
                              hipStream_t stream) {
    const float* x     = (const float*)d_in[0];
    const int*   edges = (const int*)d_in[1];   // int32 per harness contract
    const float* W1    = (const float*)d_in[2];
    const float* b1    = (const float*)d_in[3];
    const float* W2    = (const float*)d_in[4];
    const float* b2    = (const float*)d_in[5];
    float*       out   = (float*)d_out;

    const int N = in_sizes[0] / 128;   // 100000
    const int E = in_sizes[1] / 2;     // 1600000
    const int* srcIdx = edges;
    const int* dstIdx = edges + E;

    const int B1 = (N + NPB - 1) / NPB;         // 782 buckets
    const int B0 = 256;                          // phase-1 blocks
    const int chunk = (E + B0 - 1) / B0;         // 6250
    const int S  = B1 * B0;                      // scanned size (200192)
    const int nSB = (S + 2047) / 2048;           // 98 scan blocks (<=512)

    // workspace layout (256B aligned slices), ~60 MB total
    char* ws = (char*)d_ws;
    size_t off = 0;
    auto alloc = [&](size_t bytes) { char* p = ws + off; off = (off + bytes + 255) & ~(size_t)255; return p; };
    float* dinv      = (float*)alloc((size_t)N * 4);
    int*   H         = (int*)  alloc((size_t)S * 4);
    int*   blockSums = (int*)  alloc(512 * 4);
    int*   rowStart  = (int*)  alloc((size_t)(N + 1) * 4);
    int*   srcSorted = (int*)  alloc((size_t)E * 4);
    float* g1        = (float*)alloc((size_t)N * FDIM * 4);
    float* x2        = (float*)alloc((size_t)N * FDIM * 4);
    int2*  pairs     = (int2*)x2;   // alias: pairs dead before aggregate1 writes x2
    float* g2        = g1;          // g1 dead after first aggregate

    const int gT = (N + 63) / 64;   // GEMM tiles

    bucket_hist   <<<B0, 256, 0, stream>>>(dstIdx, E, B1, chunk, B0, H);
    scanA         <<<nSB, 256, 0, stream>>>(H, S, blockSums);
    scanB         <<<1, 512, 0, stream>>>(blockSums, nSB);
    scanC         <<<nSB, 256, 0, stream>>>(H, S, blockSums);
    bucket_scatter<<<B0, 256, 0, stream>>>(srcIdx, dstIdx, E, B1, chunk, B0, H, pairs);
    bucket_csr    <<<B1, 256, 0, stream>>>(pairs, H, B0, E, N, dinv, rowStart, srcSorted);

    gemm_scale<128><<<gT, 256, 0, stream>>>(x,  W1, dinv, g1, N);
    aggregate      <<<2048, 256, 0, stream>>>(g1, rowStart, srcSorted, dinv, b1, x2, N, 1);
    gemm_scale<64> <<<gT, 256, 0, stream>>>(x2, W2, dinv, g2, N);
    aggregate      <<<2048, 256, 0, stream>>>(g2, rowStart, srcSorted, dinv, b2, out, N, 0);
}

// Round 5
// 241.237 us; speedup vs baseline: 2.3257x; 1.0408x over previous
//
#include <hip/hip_runtime.h>
#include <hip/hip_bf16.h>

// 2-layer GCN on MI355X.
// out[v] = dinv[v] * ( sum_{e: dst=v} g[src_e] + g[v] ) + b,  g = (x@W) * dinv[row]
// dinv[v] = rsqrt(indeg(v) + 1)
// CSR build = bucketed counting sort, ALL atomics in LDS (no device atomics).
// Message matrices g1/g2 stored BF16 (fp32 accumulate everywhere) to halve
// the random-gather bytes in aggregate (the HBM-bound phase).

#define FDIM 64    // HID_DIM == OUT_DIM
#define NPB  128   // nodes per bucket (dst >> 7)
#define MAXB1 800  // >= ceil(100000/128)=782

// bf16 helpers (bit-level, RTN; finite data only)
static __device__ __forceinline__ unsigned short f2bf(float f) {
    unsigned int u = __float_as_uint(f);
    unsigned int r = 0x7FFFu + ((u >> 16) & 1u);
    return (unsigned short)((u + r) >> 16);
}
static __device__ __forceinline__ float bf2f(unsigned short u) {
    return __uint_as_float((unsigned int)u << 16);
}

// ---------------- phase 1a: per-block bucket histogram ----------------
__global__ __launch_bounds__(256) void bucket_hist(const int* __restrict__ dst, int E,
                                                   int B1, int chunk, int B0,
                                                   int* __restrict__ H) {
    __shared__ int hist[MAXB1];
    const int blk = blockIdx.x, t = threadIdx.x;
    for (int i = t; i < B1; i += 256) hist[i] = 0;
    __syncthreads();
    const int beg = blk * chunk, end = min(E, beg + chunk);
    for (int e = beg + t; e < end; e += 256) atomicAdd(&hist[dst[e] >> 7], 1);
    __syncthreads();
    for (int i = t; i < B1; i += 256) H[i * B0 + blk] = hist[i];  // bin-major
}

// ---------------- scan A: per-block sums over spans of 2048 ----------------
__global__ __launch_bounds__(256) void scanA(const int* __restrict__ a, int S,
                                             int* __restrict__ bs) {
    __shared__ int s[256];
    const int blk = blockIdx.x, t = threadIdx.x;
    const int base = blk * 2048 + t * 8;
    int sum = 0;
    #pragma unroll
    for (int j = 0; j < 8; ++j) { int idx = base + j; if (idx < S) sum += a[idx]; }
    s[t] = sum;
    __syncthreads();
    for (int off = 128; off > 0; off >>= 1) {
        if (t < off) s[t] += s[t + off];
        __syncthreads();
    }
    if (t == 0) bs[blk] = s[0];
}

// ---------------- scan B: exclusive scan of block sums (nB <= 512) ----------
__global__ __launch_bounds__(512) void scanB(int* __restrict__ bs, int nB) {
    __shared__ int s[512];
    const int t = threadIdx.x;
    int v = (t < nB) ? bs[t] : 0;
    s[t] = v;
    __syncthreads();
    for (int off = 1; off < 512; off <<= 1) {
        int x = s[t];
        int y = (t >= off) ? s[t - off] : 0;
        __syncthreads();
        s[t] = x + y;
        __syncthreads();
    }
    if (t < nB) bs[t] = s[t] - v;
}

// ---------------- scan C: in-place exclusive scan (span 2048/block) ---------
__global__ __launch_bounds__(256) void scanC(int* __restrict__ a, int S,
                                             const int* __restrict__ bs) {
    __shared__ int s[256];
    const int blk = blockIdx.x, t = threadIdx.x;
    const int base = blk * 2048 + t * 8;
    int v[8];
    int sum = 0;
    #pragma unroll
    for (int j = 0; j < 8; ++j) { int idx = base + j; v[j] = (idx < S) ? a[idx] : 0; sum += v[j]; }
    s[t] = sum;
    __syncthreads();
    const int own = sum;
    for (int off = 1; off < 256; off <<= 1) {
        int x = s[t];
        int y = (t >= off) ? s[t - off] : 0;
        __syncthreads();
        s[t] = x + y;
        __syncthreads();
    }
    int run = bs[blk] + s[t] - own;   // exclusive prefix for this thread's segment
    #pragma unroll
    for (int j = 0; j < 8; ++j) { int idx = base + j; if (idx < S) a[idx] = run; run += v[j]; }
}

// ------- phase 1b: scatter edges into bucket-grouped packed (dlow7,src) -----
__global__ __launch_bounds__(256) void bucket_scatter(const int* __restrict__ src,
                                                      const int* __restrict__ dst,
                                                      int E, int B1, int chunk, int B0,
                                                      const int* __restrict__ Hs,
                                                      int* __restrict__ pairs) {
    __shared__ int cur[MAXB1];
    const int blk = blockIdx.x, t = threadIdx.x;
    for (int i = t; i < B1; i += 256) cur[i] = Hs[i * B0 + blk];
    __syncthreads();
    const int beg = blk * chunk, end = min(E, beg + chunk);
    for (int e = beg + t; e < end; e += 256) {
        int d = dst[e];
        int pos = atomicAdd(&cur[d >> 7], 1);          // LDS atomic
        pairs[pos] = ((d & 127) << 17) | src[e];       // src < 2^17
    }
}

// ---------------- phase 2: per-bucket local counting sort -> CSR ------------
__global__ __launch_bounds__(256) void bucket_csr(const int* __restrict__ pairs,
                                                  const int* __restrict__ Hs,
                                                  int B0, int E, int N,
                                                  float* __restrict__ dinv,
                                                  int* __restrict__ rowStart,
                                                  int* __restrict__ srcSorted) {
    __shared__ int hist[NPB], pref[NPB], cur[NPB];
    const int b = blockIdx.x, t = threadIdx.x;
    const int B1 = gridDim.x;
    const int vbase = b * NPB;
    const int nv = min(NPB, N - vbase);
    const int estart = Hs[b * B0];
    const int eend = (b + 1 < B1) ? Hs[(b + 1) * B0] : E;

    if (t < NPB) hist[t] = 0;
    __syncthreads();
    for (int e = estart + t; e < eend; e += 256)
        atomicAdd(&hist[pairs[e] >> 17], 1);
    __syncthreads();

    if (t < NPB) pref[t] = hist[t];
    __syncthreads();
    for (int off = 1; off < NPB; off <<= 1) {
        int v = 0;
        if (t < NPB && t >= off) v = pref[t - off];
        __syncthreads();
        if (t < NPB) pref[t] += v;
        __syncthreads();
    }
    if (t < nv) {
        int ex = pref[t] - hist[t];          // exclusive prefix
        rowStart[vbase + t] = estart + ex;
        dinv[vbase + t] = rsqrtf((float)(hist[t] + 1));
        cur[t] = estart + ex;
    }
    if (b == B1 - 1 && t == 0) rowStart[N] = E;
    __syncthreads();
    for (int e = estart + t; e < eend; e += 256) {
        int p = pairs[e];
        int pos = atomicAdd(&cur[p >> 17], 1);       // LDS atomic
        srcSorted[pos] = p & 0x1FFFF;
    }
}

// ---------------- GEMM: W in LDS, 16 outputs/thread, bf16 output ------------
// Block = 256 threads, 64 rows/block. Thread t: row t/4, col-quarter t%4.
template <int K>
__global__ __launch_bounds__(256) void gemm_scale(const float* __restrict__ X,
                                                  const float* __restrict__ W,
                                                  const float* __restrict__ dinv,
                                                  unsigned short* __restrict__ G, int N) {
    __shared__ float Wl[K * FDIM];
    const int t = threadIdx.x;
    {
        const float4* Wv  = reinterpret_cast<const float4*>(W);
        float4*       Wlv = reinterpret_cast<float4*>(Wl);
        #pragma unroll
        for (int i = 0; i < (K * FDIM) / (256 * 4); ++i)
            Wlv[i * 256 + t] = Wv[i * 256 + t];
    }
    __syncthreads();

    const int r   = t >> 2;
    const int q   = t & 3;
    const int row = blockIdx.x * 64 + r;
    if (row >= N) return;

    const float4* xr  = reinterpret_cast<const float4*>(X + (size_t)row * K);
    const float4* wlq = reinterpret_cast<const float4*>(Wl) + q * 4;

    float acc[16];
    #pragma unroll
    for (int i = 0; i < 16; ++i) acc[i] = 0.f;

    #pragma unroll 2
    for (int k4 = 0; k4 < K / 4; ++k4) {
        float4 xv = xr[k4];
        float xs[4] = {xv.x, xv.y, xv.z, xv.w};
        #pragma unroll
        for (int j = 0; j < 4; ++j) {
            const float4* wrow = wlq + (size_t)(4 * k4 + j) * 16;
            float4 w0 = wrow[0], w1 = wrow[1], w2 = wrow[2], w3 = wrow[3];
            float xk = xs[j];
            acc[ 0] += xk * w0.x; acc[ 1] += xk * w0.y; acc[ 2] += xk * w0.z; acc[ 3] += xk * w0.w;
            acc[ 4] += xk * w1.x; acc[ 5] += xk * w1.y; acc[ 6] += xk * w1.z; acc[ 7] += xk * w1.w;
            acc[ 8] += xk * w2.x; acc[ 9] += xk * w2.y; acc[10] += xk * w2.z; acc[11] += xk * w2.w;
            acc[12] += xk * w3.x; acc[13] += xk * w3.y; acc[14] += xk * w3.z; acc[15] += xk * w3.w;
        }
    }

    const float dv = dinv[row];
    unsigned int p[8];
    #pragma unroll
    for (int i = 0; i < 8; ++i) {
        unsigned int lo = f2bf(acc[2 * i] * dv);
        unsigned int hi = f2bf(acc[2 * i + 1] * dv);
        p[i] = lo | (hi << 16);
    }
    uint4* gout = reinterpret_cast<uint4*>(G + (size_t)row * FDIM + q * 16);
    gout[0] = make_uint4(p[0], p[1], p[2], p[3]);
    gout[1] = make_uint4(p[4], p[5], p[6], p[7]);
}

// ------- aggregate: one wave per node, bf16 gather, fp32 accumulate ---------
__global__ __launch_bounds__(256) void aggregate(const unsigned short* __restrict__ G,
                                                 const int* __restrict__ rowStart,
                                                 const int* __restrict__ srcSorted,
                                                 const float* __restrict__ dinv,
                                                 const float* __restrict__ bias,
                                                 float* __restrict__ OUT, int N, int doRelu) {
    const int lane   = threadIdx.x & 63;
    const int waveId = blockIdx.x * (blockDim.x >> 6) + (threadIdx.x >> 6);
    const int nWaves = gridDim.x * (blockDim.x >> 6);
    const float b = bias[lane];

    for (int v = waveId; v < N; v += nWaves) {
        int beg = rowStart[v], end = rowStart[v + 1];
        float acc = bf2f(G[(size_t)v * FDIM + lane]);   // self loop
        int e = beg;
        for (; e + 4 <= end; e += 4) {
            int s0 = srcSorted[e + 0];
            int s1 = srcSorted[e + 1];
            int s2 = srcSorted[e + 2];
            int s3 = srcSorted[e + 3];
            float v0 = bf2f(G[(size_t)s0 * FDIM + lane]);
            float v1 = bf2f(G[(size_t)s1 * FDIM + lane]);
            float v2 = bf2f(G[(size_t)s2 * FDIM + lane]);
            float v3 = bf2f(G[(size_t)s3 * FDIM + lane]);
            acc += v0; acc += v1; acc += v2; acc += v3;
        }
        for (; e < end; ++e) acc += bf2f(G[(size_t)srcSorted[e] * FDIM + lane]);
        float r = acc * dinv[v] + b;
        if (doRelu) r = fmaxf(r, 0.f);
        OUT[(size_t)v * FDIM + lane] = r;
    }
}

extern "C" void kernel_launch(void* const* d_in, const int* in_sizes, int n_in,
                              void* d_out, int out_size, void* d_ws, size_t ws_size,
                              hipStream_t stream) {
    const float* x     = (const float*)d_in[0];
    const int*   edges = (const int*)d_in[1];   // int32 per harness contract
    const float* W1    = (const float*)d_in[2];
    const float* b1    = (const float*)d_in[3];
    const float* W2    = (const float*)d_in[4];
    const float* b2    = (const float*)d_in[5];
    float*       out   = (float*)d_out;

    const int N = in_sizes[0] / 128;   // 100000
    const int E = in_sizes[1] / 2;     // 1600000
    const int* srcIdx = edges;
    const int* dstIdx = edges + E;

    const int B1 = (N + NPB - 1) / NPB;         // 782 buckets
    const int B0 = 256;                          // phase-1 blocks
    const int chunk = (E + B0 - 1) / B0;         // 6250
    const int S  = B1 * B0;                      // scanned size (200192)
    const int nSB = (S + 2047) / 2048;           // 98 scan blocks (<=512)

    // workspace layout (256B aligned slices)
    char* ws = (char*)d_ws;
    size_t off = 0;
    auto alloc = [&](size_t bytes) { char* p = ws + off; off = (off + bytes + 255) & ~(size_t)255; return p; };
    float* dinv      = (float*)alloc((size_t)N * 4);
    int*   H         = (int*)  alloc((size_t)S * 4);
    int*   blockSums = (int*)  alloc(512 * 4);
    int*   rowStart  = (int*)  alloc((size_t)(N + 1) * 4);
    int*   srcSorted = (int*)  alloc((size_t)E * 4);
    unsigned short* g1 = (unsigned short*)alloc((size_t)N * FDIM * 2);  // bf16
    float* x2        = (float*)alloc((size_t)N * FDIM * 4);
    int*   pairs     = (int*)x2;        // alias: pairs dead before x2 written
    unsigned short* g2 = g1;            // g1 dead after first aggregate

    const int gT = (N + 63) / 64;   // GEMM tiles

    bucket_hist   <<<B0, 256, 0, stream>>>(dstIdx, E, B1, chunk, B0, H);
    scanA         <<<nSB, 256, 0, stream>>>(H, S, blockSums);
    scanB         <<<1, 512, 0, stream>>>(blockSums, nSB);
    scanC         <<<nSB, 256, 0, stream>>>(H, S, blockSums);
    bucket_scatter<<<B0, 256, 0, stream>>>(srcIdx, dstIdx, E, B1, chunk, B0, H, pairs);
    bucket_csr    <<<B1, 256, 0, stream>>>(pairs, H, B0, E, N, dinv, rowStart, srcSorted);

    gemm_scale<128><<<gT, 256, 0, stream>>>(x,  W1, dinv, g1, N);
    aggregate      <<<2048, 256, 0, stream>>>(g1, rowStart, srcSorted, dinv, b1, x2, N, 1);
    gemm_scale<64> <<<gT, 256, 0, stream>>>(x2, W2, dinv, g2, N);
    aggregate      <<<2048, 256, 0, stream>>>(g2, rowStart, srcSorted, dinv, b2, out, N, 0);
}